// Round 7
// baseline (60.763 us; speedup 1.0000x reference)
//
#include <hip/hip_runtime.h>
#include <math.h>

// Problem constants (fixed shapes from reference)
#define BATCH   8
#define HGRID   64
#define WGRID   64
#define DDIM    256
#define NPTS    1024
#define ROWS    65          // HGRID + 1 (NaN pad row 0)
#define COLS    65
#define KWIN    15
#define BN      (BATCH*NPTS)

typedef __attribute__((ext_vector_type(8))) short bf16x8;
typedef __attribute__((ext_vector_type(4))) float f32x4;

// ---------------------------------------------------------------------------
// Kernel 1: split c_t (fp32) -> CH, CL (bf16 truncation + residual-bf16)
// 2048 blocks x 256 thr x 4 floats = 2,097,152 elements
// ---------------------------------------------------------------------------
__global__ __launch_bounds__(256) void convert_ct(const float* __restrict__ ct,
                                                  ushort* __restrict__ CH,
                                                  ushort* __restrict__ CL) {
    const int i = (blockIdx.x * 256 + threadIdx.x) * 4;
    const float4 v = *reinterpret_cast<const float4*>(&ct[i]);
    const float f[4] = {v.x, v.y, v.z, v.w};
    ushort h[4], l[4];
    #pragma unroll
    for (int e = 0; e < 4; ++e) {
        const unsigned u = __float_as_uint(f[e]);
        h[e] = (ushort)(u >> 16);
        const float res = f[e] - __uint_as_float(u & 0xFFFF0000u);
        l[e] = (ushort)(__float_as_uint(res) >> 16);
    }
    *reinterpret_cast<ushort4*>(&CH[i]) = make_ushort4(h[0], h[1], h[2], h[3]);
    *reinterpret_cast<ushort4*>(&CL[i]) = make_ushort4(l[0], l[1], l[2], l[3]);
}

// ---------------------------------------------------------------------------
// Kernel 2: split + TRANSPOSE W_a: W[c][d] -> WHT[d][c], WLT[d][c] (bf16)
// 256 blocks (d) x 256 thr (c)
// ---------------------------------------------------------------------------
__global__ __launch_bounds__(256) void convert_w(const float* __restrict__ W,
                                                 ushort* __restrict__ WHT,
                                                 ushort* __restrict__ WLT) {
    const int d = blockIdx.x;
    const int c = threadIdx.x;
    const float f = W[c * DDIM + d];
    const unsigned u = __float_as_uint(f);
    const ushort h = (ushort)(u >> 16);
    const float res = f - __uint_as_float(u & 0xFFFF0000u);
    WHT[d * DDIM + c] = h;
    WLT[d * DDIM + c] = (ushort)(__float_as_uint(res) >> 16);
}

// ---------------------------------------------------------------------------
// Kernel 3: proj[m,d] = sum_c c_t[m,c] * W_a[c,d]  via 3-term split-bf16 MFMA.
// Block 256 thr (4 waves). BM=64 (wave: 16 rows x 64 cols). BN=64.
// Grid (128, 4). B k-tiles staged in LDS (pitch 40 shorts -> 16B-aligned
// ds_read_b128, <=2-way bank conflicts). A frags straight from global.
// ---------------------------------------------------------------------------
__global__ __launch_bounds__(256) void proj_gemm(const ushort* __restrict__ CH,
                                                 const ushort* __restrict__ CL,
                                                 const ushort* __restrict__ WHT,
                                                 const ushort* __restrict__ WLT,
                                                 float* __restrict__ P) {
    __shared__ __align__(16) ushort BHs[64][40];   // [col][k] pitch 80B
    __shared__ __align__(16) ushort BLs[64][40];

    const int t    = threadIdx.x;
    const int wv   = t >> 6;
    const int lane = t & 63;
    const int l15  = lane & 15;
    const int g    = lane >> 4;            // k-subgroup 0..3
    const int m0   = blockIdx.x * 64;
    const int n0   = blockIdx.y * 64;
    const int scol  = t >> 2;              // staging: col 0..63
    const int spart = t & 3;               // staging: k-part 0..3 (8 shorts each)

    f32x4 acc[4];
    #pragma unroll
    for (int df = 0; df < 4; ++df) acc[df] = (f32x4)0.0f;

    const int arow = m0 + wv * 16 + l15;

    for (int kt = 0; kt < 8; ++kt) {
        __syncthreads();                   // previous-iter readers done
        *reinterpret_cast<uint4*>(&BHs[scol][spart * 8]) =
            *reinterpret_cast<const uint4*>(&WHT[(n0 + scol) * DDIM + kt * 32 + spart * 8]);
        *reinterpret_cast<uint4*>(&BLs[scol][spart * 8]) =
            *reinterpret_cast<const uint4*>(&WLT[(n0 + scol) * DDIM + kt * 32 + spart * 8]);
        __syncthreads();

        union { uint4 u; bf16x8 v; } AH, AL;
        AH.u = *reinterpret_cast<const uint4*>(&CH[(size_t)arow * DDIM + kt * 32 + g * 8]);
        AL.u = *reinterpret_cast<const uint4*>(&CL[(size_t)arow * DDIM + kt * 32 + g * 8]);

        #pragma unroll
        for (int df = 0; df < 4; ++df) {
            union { uint4 u; bf16x8 v; } BH, BL;
            BH.u = *reinterpret_cast<const uint4*>(&BHs[df * 16 + l15][g * 8]);
            BL.u = *reinterpret_cast<const uint4*>(&BLs[df * 16 + l15][g * 8]);
            acc[df] = __builtin_amdgcn_mfma_f32_16x16x32_bf16(AH.v, BH.v, acc[df], 0, 0, 0);
            acc[df] = __builtin_amdgcn_mfma_f32_16x16x32_bf16(AH.v, BL.v, acc[df], 0, 0, 0);
            acc[df] = __builtin_amdgcn_mfma_f32_16x16x32_bf16(AL.v, BH.v, acc[df], 0, 0, 0);
        }
    }

    // C/D layout: col = lane&15, row = (lane>>4)*4 + reg  [m89-verified]
    #pragma unroll
    for (int df = 0; df < 4; ++df)
        #pragma unroll
        for (int r = 0; r < 4; ++r)
            P[(size_t)(m0 + wv * 16 + g * 4 + r) * DDIM + n0 + df * 16 + l15] = acc[df][r];
}

// ---------------------------------------------------------------------------
// Kernel 4: two-pass local attention. One wave per pid; lane owns d=lane*4..+3.
// Pass 1: 15 independent gathers -> partial dots -> pipelined butterfly
// reductions. Softmax once. Pass 2: re-gather (L1/L2-hot) weighted sum.
// No qg array -> small VGPR; (256,8) -> 8 waves/SIMD, 8192 waves total.
// ---------------------------------------------------------------------------
__global__ __launch_bounds__(256, 8) void local_attn(const float* __restrict__ q,
                                                     const float* __restrict__ p_t,
                                                     const float* __restrict__ proj,
                                                     float* __restrict__ out) {
    const int w    = threadIdx.x >> 6;
    const int lane = threadIdx.x & 63;
    const int pid  = blockIdx.x * 4 + w;
    const int b    = pid >> 10;
    const float2 pp = *reinterpret_cast<const float2*>(&p_t[pid * 2]);
    const float p0f = pp.x;
    const float p1f = pp.y;
    const int p0 = (int)p0f;
    const int p1 = (int)p1f;

    const float4 pr = *reinterpret_cast<const float4*>(&proj[(size_t)pid * DDIM + lane * 4]);

    float re[3], ce[5];
    int rowidx[3], colidx[5];
    #pragma unroll
    for (int i = 0; i < 3; ++i) {
        int rr = p0 + i;
        rr = rr > ROWS ? ROWS : rr;
        rr = (rr == ROWS) ? 0 : rr;        // % ROWS
        rowidx[i] = rr;
        const float rf = (float)(rr - 1 > 0 ? rr - 1 : 0);
        const float dr = rf - p0f;         // / R_WIN (=1)
        re[i] = __expf(-2.0f * dr * dr);
    }
    #pragma unroll
    for (int j = 0; j < 5; ++j) {
        int cc = p1 + j - 1;
        cc = cc < 0 ? 0 : (cc > COLS ? COLS : cc);
        cc = (cc == COLS) ? 0 : cc;        // % COLS
        colidx[j] = cc;
        const float cf = (float)(cc - 1 > 0 ? cc - 1 : 0);
        const float dc = (cf - p1f) * 0.5f; // / C_WIN (=2)
        ce[j] = __expf(-2.0f * dc * dc);
    }

    float score[KWIN];

    // ---- Pass 1: partial dots (15 independent loads -> MLP) ----
    #pragma unroll
    for (int i = 0; i < 3; ++i) {
        #pragma unroll
        for (int j = 0; j < 5; ++j) {
            const int k  = i * 5 + j;
            const int rr = rowidx[i];
            const int cc = colidx[j];
            float s = 0.f;
            if ((rr != 0) && (cc != 0)) {              // wave-uniform
                const float4 v = *reinterpret_cast<const float4*>(
                    &q[((size_t)((b * HGRID + rr - 1) * WGRID + cc - 1)) * DDIM
                       + lane * 4]);
                s = fmaf(v.x, pr.x, fmaf(v.y, pr.y, fmaf(v.z, pr.z, v.w * pr.w)));
            }
            score[k] = s;
        }
    }

    // ---- Butterfly reductions (independent -> pipelined) ----
    #pragma unroll
    for (int k = 0; k < KWIN; ++k) {
        float s = score[k];
        #pragma unroll
        for (int off = 32; off; off >>= 1) s += __shfl_xor(s, off, 64);
        score[k] = s;
    }
    #pragma unroll
    for (int i = 0; i < 3; ++i)
        #pragma unroll
        for (int j = 0; j < 5; ++j)
            if ((rowidx[i] == 0) || (colidx[j] == 0)) score[i * 5 + j] = -INFINITY;

    // ---- Softmax over K=15 ----
    float mx = score[0];
    #pragma unroll
    for (int k = 1; k < KWIN; ++k) mx = fmaxf(mx, score[k]);
    float sum = 0.f;
    #pragma unroll
    for (int k = 0; k < KWIN; ++k) {
        const float e = __expf(score[k] - mx);
        score[k] = e;
        sum += e;
    }
    const float inv = 1.0f / sum;

    // ---- Pass 2: re-gather (cache-hot), weighted sum ----
    float ox = 0.f, oy = 0.f, oz = 0.f, ow = 0.f;
    #pragma unroll
    for (int i = 0; i < 3; ++i) {
        #pragma unroll
        for (int j = 0; j < 5; ++j) {
            const int k  = i * 5 + j;
            const int rr = rowidx[i];
            const int cc = colidx[j];
            if ((rr != 0) && (cc != 0)) {
                const float4 v = *reinterpret_cast<const float4*>(
                    &q[((size_t)((b * HGRID + rr - 1) * WGRID + cc - 1)) * DDIM
                       + lane * 4]);
                const float wk = score[k] * inv * re[i] * ce[j];
                ox = fmaf(wk, v.x, ox);
                oy = fmaf(wk, v.y, oy);
                oz = fmaf(wk, v.z, oz);
                ow = fmaf(wk, v.w, ow);
            }
        }
    }
    *reinterpret_cast<float4*>(&out[(size_t)pid * DDIM + lane * 4]) =
        make_float4(ox, oy, oz, ow);
}

// ---------------------------------------------------------------------------
extern "C" void kernel_launch(void* const* d_in, const int* in_sizes, int n_in,
                              void* d_out, int out_size, void* d_ws, size_t ws_size,
                              hipStream_t stream) {
    const float* q   = (const float*)d_in[0];
    const float* c_t = (const float*)d_in[1];
    const float* p_t = (const float*)d_in[2];
    const float* W_a = (const float*)d_in[3];
    float* out = (float*)d_out;

    char* ws = (char*)d_ws;
    float*  proj = (float*)ws;                          // 8 MB
    ushort* CH   = (ushort*)(ws + (8  << 20));          // 4 MB
    ushort* CL   = (ushort*)(ws + (12 << 20));          // 4 MB
    ushort* WHT  = (ushort*)(ws + (16 << 20));          // 128 KB
    ushort* WLT  = (ushort*)(ws + (16 << 20) + (DDIM * DDIM * 2));

    convert_ct<<<BN * DDIM / (256 * 4), 256, 0, stream>>>(c_t, CH, CL);
    convert_w <<<DDIM, 256, 0, stream>>>(W_a, WHT, WLT);

    dim3 gemm_grid(BN / 64, DDIM / 64);                 // 128 x 4
    proj_gemm<<<gemm_grid, 256, 0, stream>>>(CH, CL, WHT, WLT, proj);

    local_attn<<<BN / 4, 256, 0, stream>>>(q, p_t, proj, out);
}

// Round 8
// 47.730 us; speedup vs baseline: 1.2731x; 1.2731x over previous
//
#include <hip/hip_runtime.h>
#include <math.h>

// Problem constants (fixed shapes from reference)
#define BATCH   8
#define HGRID   64
#define WGRID   64
#define DDIM    256
#define NPTS    1024
#define ROWS    65          // HGRID + 1 (NaN pad row 0)
#define COLS    65
#define KWIN    15          // (2*R_WIN+1)*(2*C_WIN+1) = 3*5
#define BN      (BATCH*NPTS)

#define PIDS_PER_BLK 8
#define THREADS      512    // 8 waves, 1 pid per wave in Phase B
#define PR_PITCH     260

typedef __attribute__((ext_vector_type(8))) short bf16x8;
typedef __attribute__((ext_vector_type(4))) float f32x4;

// ---------------------------------------------------------------------------
// Fused v4: per block of 8 points,
//   Phase A (no barriers): proj[8][256] = c_t rows x W_a, split-bf16 MFMA,
//     W read per-wave from global (L2-hot). MFMA rows 8..15 are duplicates.
//   one __syncthreads()
//   Phase B: batch local attention, ONE pid per wave, single gather pass;
//     qg pinned in VGPRs via asm (defeats compiler rematerialization).
// __launch_bounds__(512,4): 128-VGPR cap, est live ~115. Grid 1024 blocks.
// ---------------------------------------------------------------------------
__global__ __launch_bounds__(THREADS, 4) void fused_local_attn(
        const float* __restrict__ q,
        const float* __restrict__ c_t,
        const float* __restrict__ p_t,
        const float* __restrict__ W,
        float* __restrict__ out) {

    __shared__ __align__(16) float Pr[PIDS_PER_BLK][PR_PITCH]; // proj rows (8.3 KB)

    const int t    = threadIdx.x;
    const int w    = t >> 6;          // wave 0..7
    const int lane = t & 63;
    const int l15  = lane & 15;
    const int g    = lane >> 4;       // k-group 0..3
    const int pid0 = blockIdx.x * PIDS_PER_BLK;
    const int dq   = w * 32;          // this wave's 32-col d-slice

    // ---------------- Phase A: proj into LDS (no barriers) ----------------
    f32x4 acc0 = (f32x4)0.f;
    f32x4 acc1 = (f32x4)0.f;

    const float* ap  = &c_t[(size_t)(pid0 + (l15 & 7)) * DDIM + g * 8];
    const float* wp0 = &W[(size_t)(g * 8) * DDIM + dq + l15];        // df=0
    const float* wp1 = wp0 + 16;                                      // df=1

    for (int kt = 0; kt < 8; ++kt) {
        // A fragment: 8 contiguous c-values of this lane's c_t row
        const float4 a01 = *reinterpret_cast<const float4*>(ap + kt * 32);
        const float4 a23 = *reinterpret_cast<const float4*>(ap + kt * 32 + 4);
        const float af[8] = {a01.x, a01.y, a01.z, a01.w, a23.x, a23.y, a23.z, a23.w};
        union { bf16x8 v; unsigned u[4]; } AH, AL;
        #pragma unroll
        for (int i = 0; i < 4; ++i) {
            const unsigned u0 = __float_as_uint(af[2 * i]);
            const unsigned u1 = __float_as_uint(af[2 * i + 1]);
            AH.u[i] = __builtin_amdgcn_perm(u1, u0, 0x07060302u);
            const float l0 = af[2 * i]     - __uint_as_float(u0 & 0xFFFF0000u);
            const float l1 = af[2 * i + 1] - __uint_as_float(u1 & 0xFFFF0000u);
            AL.u[i] = __builtin_amdgcn_perm(__float_as_uint(l1), __float_as_uint(l0),
                                            0x07060302u);
        }

        #pragma unroll
        for (int df = 0; df < 2; ++df) {
            const float* wp = (df == 0) ? wp0 : wp1;
            float bf[8];
            #pragma unroll
            for (int i = 0; i < 8; ++i)
                bf[i] = wp[(size_t)(kt * 32 + i) * DDIM];
            union { bf16x8 v; unsigned u[4]; } BH, BL;
            #pragma unroll
            for (int i = 0; i < 4; ++i) {
                const unsigned u0 = __float_as_uint(bf[2 * i]);
                const unsigned u1 = __float_as_uint(bf[2 * i + 1]);
                BH.u[i] = __builtin_amdgcn_perm(u1, u0, 0x07060302u);
                const float l0 = bf[2 * i]     - __uint_as_float(u0 & 0xFFFF0000u);
                const float l1 = bf[2 * i + 1] - __uint_as_float(u1 & 0xFFFF0000u);
                BL.u[i] = __builtin_amdgcn_perm(__float_as_uint(l1), __float_as_uint(l0),
                                                0x07060302u);
            }
            f32x4 a = (df == 0) ? acc0 : acc1;
            a = __builtin_amdgcn_mfma_f32_16x16x32_bf16(AH.v, BH.v, a, 0, 0, 0);
            a = __builtin_amdgcn_mfma_f32_16x16x32_bf16(AH.v, BL.v, a, 0, 0, 0);
            a = __builtin_amdgcn_mfma_f32_16x16x32_bf16(AL.v, BH.v, a, 0, 0, 0);
            if (df == 0) acc0 = a; else acc1 = a;
        }
    }

    // C/D layout: col = lane&15, row = (lane>>4)*4 + reg  [m89-verified]
    // Only rows 0..7 are real points (g < 2).
    if (g < 2) {
        #pragma unroll
        for (int r = 0; r < 4; ++r) {
            Pr[g * 4 + r][dq +  0 + l15] = acc0[r];
            Pr[g * 4 + r][dq + 16 + l15] = acc1[r];
        }
    }
    __syncthreads();

    // ---------------- Phase B: batch attention, 1 pid/wave ----------------
    const int pid = pid0 + w;
    const int b   = pid >> 10;             // / NPTS
    const float2 ppos = *reinterpret_cast<const float2*>(&p_t[pid * 2]);
    const float p0f = ppos.x;
    const float p1f = ppos.y;
    const int p0 = (int)p0f;
    const int p1 = (int)p1f;

    const float4 pr = *reinterpret_cast<const float4*>(&Pr[w][lane * 4]);

    float re[3], ce[5];
    int rowidx[3], colidx[5];
    #pragma unroll
    for (int i = 0; i < 3; ++i) {
        int rr = p0 + i;
        rr = rr > ROWS ? ROWS : rr;
        rr = (rr == ROWS) ? 0 : rr;        // % ROWS
        rowidx[i] = rr;
        const float rf = (float)(rr - 1 > 0 ? rr - 1 : 0);
        const float dr = rf - p0f;         // / R_WIN (=1)
        re[i] = __expf(-2.0f * dr * dr);
    }
    #pragma unroll
    for (int j = 0; j < 5; ++j) {
        int cc = p1 + j - 1;
        cc = cc < 0 ? 0 : (cc > COLS ? COLS : cc);
        cc = (cc == COLS) ? 0 : cc;        // % COLS
        colidx[j] = cc;
        const float cf = (float)(cc - 1 > 0 ? cc - 1 : 0);
        const float dc = (cf - p1f) * 0.5f; // / C_WIN (=2)
        ce[j] = __expf(-2.0f * dc * dc);
    }

    float4 qg[KWIN];
    float score[KWIN];
    unsigned vmask = 0;

    // ---- Single gather pass; pin each loaded row in VGPRs (no remat) ----
    #pragma unroll
    for (int i = 0; i < 3; ++i) {
        #pragma unroll
        for (int j = 0; j < 5; ++j) {
            const int k  = i * 5 + j;
            const int rr = rowidx[i];
            const int cc = colidx[j];
            const bool valid = (rr != 0) && (cc != 0);   // wave-uniform
            float s = 0.f;
            float4 v = make_float4(0.f, 0.f, 0.f, 0.f);
            if (valid) {
                v = *reinterpret_cast<const float4*>(
                    &q[((size_t)((b * HGRID + rr - 1) * WGRID + cc - 1)) * DDIM
                       + lane * 4]);
                asm volatile("" : "+v"(v.x), "+v"(v.y), "+v"(v.z), "+v"(v.w));
                s = fmaf(v.x, pr.x, fmaf(v.y, pr.y, fmaf(v.z, pr.z, v.w * pr.w)));
                vmask |= (1u << k);
            }
            qg[k] = v;
            score[k] = s;
        }
    }

    // ---- 15 independent butterfly reductions (pipelined) ----
    #pragma unroll
    for (int k = 0; k < KWIN; ++k) {
        float s = score[k];
        #pragma unroll
        for (int off = 32; off; off >>= 1) s += __shfl_xor(s, off, 64);
        score[k] = ((vmask >> k) & 1u) ? s : -INFINITY;
    }

    // ---- Softmax over K=15 (replicated across lanes) ----
    float mx = score[0];
    #pragma unroll
    for (int k = 1; k < KWIN; ++k) mx = fmaxf(mx, score[k]);
    float sum = 0.f;
    #pragma unroll
    for (int k = 0; k < KWIN; ++k) {
        const float e = __expf(score[k] - mx);
        score[k] = e;
        sum += e;
    }
    const float inv = 1.0f / sum;

    // ---- Weighted sum from pinned registers ----
    float ox = 0.f, oy = 0.f, oz = 0.f, ow = 0.f;
    #pragma unroll
    for (int i = 0; i < 3; ++i) {
        #pragma unroll
        for (int j = 0; j < 5; ++j) {
            const int k = i * 5 + j;
            const float wk = score[k] * inv * re[i] * ce[j];
            ox = fmaf(wk, qg[k].x, ox);
            oy = fmaf(wk, qg[k].y, oy);
            oz = fmaf(wk, qg[k].z, oz);
            ow = fmaf(wk, qg[k].w, ow);
        }
    }
    *reinterpret_cast<float4*>(&out[(size_t)pid * DDIM + lane * 4]) =
        make_float4(ox, oy, oz, ow);
}

// ---------------------------------------------------------------------------
extern "C" void kernel_launch(void* const* d_in, const int* in_sizes, int n_in,
                              void* d_out, int out_size, void* d_ws, size_t ws_size,
                              hipStream_t stream) {
    const float* q   = (const float*)d_in[0];
    const float* c_t = (const float*)d_in[1];
    const float* p_t = (const float*)d_in[2];
    const float* W_a = (const float*)d_in[3];
    float* out = (float*)d_out;

    fused_local_attn<<<BN / PIDS_PER_BLK, THREADS, 0, stream>>>(q, c_t, p_t, W_a, out);
}